// Round 3
// baseline (523.195 us; speedup 1.0000x reference)
//
#include <hip/hip_runtime.h>
#include <cstdint>

// ---------------------------------------------------------------------------
// MultiHeadAttention (B=8,S=1024,D=1024,H=16,E=64). Inputs fp32, output fp32.
// Quirks: scale = 1/sqrt(8) (d_k = batch quirk); tril + exact-zero -> -1e9
// (fp32, pre-round); softmax over HEADS axis (local per (b,q,k)).
//
// R10: deterministic balanced triangle via k-parity split.
//  - attn: back to proven 32-q-row/1024-thread/16-warp shape (R7 per-row
//    efficiency); 256 blocks, 1 block/CU, ONE dispatch round.
//  - block (b,j) runs TWO tasks: even-kt half of qt=j, then odd-kt half of
//    qt=31-j  ->  16-17 iterations per block, perfectly balanced.
//  - partial O's meet via fp32 unsafeAtomicAdd into zeroed P (exactly 2
//    commutative contributors -> deterministic).  P aliases X1b/X2b (dead).
//  - uniform tail (k>q: all heads masked -> attn==1/16) in the odd task,
//    length 32*j, anti-correlated with iter count -> balances.
//  - b = blockIdx&7 == XCD -> per-XCD single-batch K/V (R9's accidental
//    FETCH 139->25MB win, kept deliberately).
//  - V double-buffer register prefetch issued ~2 barriers before use;
//    2 barriers/iter; scf padded [34] (4-way write conflict -> 2-way free).
//  - GEMMs reverted to R7 bf16 global_load_lds path (R9 a_f32 cost +27us).
// ---------------------------------------------------------------------------

typedef unsigned short u16;
typedef unsigned int   u32;
typedef __attribute__((ext_vector_type(8))) __bf16         bf16x8;
typedef __attribute__((ext_vector_type(8))) unsigned short ushort8;
typedef __attribute__((ext_vector_type(4))) float          f32x4;

#define S_ 1024
#define D_ 1024
#define H_ 16
#define E_ 64

__device__ __forceinline__ float b2f(u16 h) {
  union { u32 u; float f; } v; v.u = ((u32)h) << 16; return v.f;
}
__device__ __forceinline__ u16 f2b(float f) {      // round-to-nearest-even
  union { float f; u32 u; } v; v.f = f;
  u32 r = v.u + 0x7fffu + ((v.u >> 16) & 1u);
  return (u16)(r >> 16);
}

typedef const __attribute__((address_space(1))) u32 gu32;
typedef       __attribute__((address_space(3))) u32 lu32;

// 16B global->LDS direct load; LDS dest must be wave-uniform base + lane*16.
__device__ __forceinline__ void gload_lds16(const u16* g, u16* l) {
  __builtin_amdgcn_global_load_lds((gu32*)(uintptr_t)g, (lu32*)(uintptr_t)l,
                                   16, 0, 0);
}

// ---------------------------------------------------------------------------
// fp32 -> bf16 elementwise convert (n = multiple of 2048).
// ---------------------------------------------------------------------------
__global__ __launch_bounds__(256, 1) void cvt_bf16(
    const float* __restrict__ src, u16* __restrict__ dst)
{
  const size_t i = (size_t)blockIdx.x * 256 + threadIdx.x;
  float4 a = ((const float4*)src)[2 * i];
  float4 b = ((const float4*)src)[2 * i + 1];
  ushort8 o;
  o[0] = f2b(a.x); o[1] = f2b(a.y); o[2] = f2b(a.z); o[3] = f2b(a.w);
  o[4] = f2b(b.x); o[5] = f2b(b.y); o[6] = f2b(b.z); o[7] = f2b(b.w);
  ((ushort8*)dst)[i] = o;
}

// ---------------------------------------------------------------------------
// Weight transpose+convert: W fp32 [K][N] -> Wt bf16 [N][K]. 64x64 tiles.
// ---------------------------------------------------------------------------
__global__ __launch_bounds__(256, 1) void trans_cvt_w(
    const float* __restrict__ W, u16* __restrict__ Wt)
{
  __shared__ u16 t[64][72];
  const int k0 = blockIdx.x * 64, n0 = blockIdx.y * 64;
  const int row = threadIdx.x >> 3;
  const int cs  = (threadIdx.x & 7) * 8;
#pragma unroll
  for (int p = 0; p < 2; ++p) {
    int r = row + p * 32;
    const float* Wp = W + (size_t)(k0 + r) * 1024 + n0 + cs;
    float4 a = *(const float4*)(Wp);
    float4 b = *(const float4*)(Wp + 4);
    u16* tp = &t[r][cs];
    tp[0] = f2b(a.x); tp[1] = f2b(a.y); tp[2] = f2b(a.z); tp[3] = f2b(a.w);
    tp[4] = f2b(b.x); tp[5] = f2b(b.y); tp[6] = f2b(b.z); tp[7] = f2b(b.w);
  }
  __syncthreads();
#pragma unroll
  for (int p = 0; p < 2; ++p) {
    int n = row + p * 32;
    ushort8 v;
#pragma unroll
    for (int i = 0; i < 8; ++i) v[i] = t[cs + i][n];
    *(ushort8*)(Wt + (size_t)(n0 + n) * 1024 + k0 + cs) = v;
  }
}

// ---------------------------------------------------------------------------
// bf16 MFMA GEMM: C[M][N] = A[M][K] @ Bt[N][K]^T + bias[N] (fp32 accum).
// 128x128 tile, BK=32, 256 threads / 4 waves. m97-style global_load_lds
// width-16 staging. out_f32: 1 -> fp32 stores, 0 -> bf16 stores.
// ---------------------------------------------------------------------------
__global__ __launch_bounds__(256, 1) void gemm_bf16(
    const u16* __restrict__ A, const u16* __restrict__ Bt,
    const float* __restrict__ bias, void* __restrict__ Cv,
    int M, int N, int K, int out_f32)
{
  __shared__ u16 As[128 * 32];   // [m][k] row-major, 8KB
  __shared__ u16 Bs[128 * 32];   // [n][k] row-major, 8KB
  const int tid  = threadIdx.x;
  const int wave = tid >> 6;
  const int lane = tid & 63;
  const int quad = lane >> 4;
  const int l16  = lane & 15;
  const int m0   = (wave & 1) * 64;
  const int n0   = (wave >> 1) * 64;

  const u16* Ab = A  + (size_t)blockIdx.x * 128 * K;
  const u16* Bb = Bt + (size_t)blockIdx.y * 128 * K;

  f32x4 acc[4][4];
#pragma unroll
  for (int i = 0; i < 4; ++i)
#pragma unroll
    for (int j = 0; j < 4; ++j) acc[i][j] = (f32x4){0.f, 0.f, 0.f, 0.f};

  for (int kb = 0; kb < K; kb += 32) {
    __syncthreads();               // prior iter's LDS reads done
#pragma unroll
    for (int p = 0; p < 2; ++p) {  // 512 16B segs over 256 threads
      int seg = tid + p * 256;     // = (wave*64+p*256) + lane -> base+lane*16
      int row = seg >> 2, ks = seg & 3;
      gload_lds16(Ab + (size_t)row * K + kb + ks * 8, As + seg * 8);
      gload_lds16(Bb + (size_t)row * K + kb + ks * 8, Bs + seg * 8);
    }
    __builtin_amdgcn_s_waitcnt(0); // drain vmcnt before barrier
    __syncthreads();

    bf16x8 af[4], bfr[4];
#pragma unroll
    for (int i = 0; i < 4; ++i)    // A-frag: m=lane&15, k=quad*8+j
      af[i] = *(const bf16x8*)(As + (m0 + i * 16 + l16) * 32 + quad * 8);
#pragma unroll
    for (int j = 0; j < 4; ++j)    // B-frag: n=lane&15, k=quad*8+j
      bfr[j] = *(const bf16x8*)(Bs + (n0 + j * 16 + l16) * 32 + quad * 8);
#pragma unroll
    for (int i = 0; i < 4; ++i)
#pragma unroll
      for (int j = 0; j < 4; ++j)
        acc[i][j] = __builtin_amdgcn_mfma_f32_16x16x32_bf16(
            af[i], bfr[j], acc[i][j], 0, 0, 0);
  }

  float bv[4];
#pragma unroll
  for (int j = 0; j < 4; ++j)
    bv[j] = bias[(size_t)blockIdx.y * 128 + n0 + j * 16 + l16];

  if (out_f32) {
    float* C = (float*)Cv;
#pragma unroll
    for (int i = 0; i < 4; ++i) {
      int r = blockIdx.x * 128 + m0 + i * 16 + quad * 4;   // row=quad*4+reg
#pragma unroll
      for (int j = 0; j < 4; ++j) {
        int c = blockIdx.y * 128 + n0 + j * 16 + l16;      // col=lane&15
#pragma unroll
        for (int reg = 0; reg < 4; ++reg)
          C[(size_t)(r + reg) * N + c] = acc[i][j][reg] + bv[j];
      }
    }
  } else {
    u16* C = (u16*)Cv;
#pragma unroll
    for (int i = 0; i < 4; ++i) {
      int r = blockIdx.x * 128 + m0 + i * 16 + quad * 4;
#pragma unroll
      for (int j = 0; j < 4; ++j) {
        int c = blockIdx.y * 128 + n0 + j * 16 + l16;
#pragma unroll
        for (int reg = 0; reg < 4; ++reg)
          C[(size_t)(r + reg) * N + c] = f2b(acc[i][j][reg] + bv[j]);
      }
    }
  }
}

// ---------------------------------------------------------------------------
// V transpose (bf16): V[b][s][h*64+e] -> Vt[(b*16+h)*64+e][s]  (per-head E,S)
// ---------------------------------------------------------------------------
__global__ __launch_bounds__(256, 1) void transpose_v(
    const u16* __restrict__ V, u16* __restrict__ Vt)
{
  __shared__ u16 t[64][72];
  const int s0 = blockIdx.x * 64;
  const int bh = blockIdx.y;           // b*16 + h
  const int b = bh >> 4, h = bh & 15;
  const int row = threadIdx.x >> 3;
  const int cs  = (threadIdx.x & 7) * 8;
#pragma unroll
  for (int p = 0; p < 2; ++p) {
    int s = row + p * 32;
    *(ushort8*)(&t[s][cs]) = *(const ushort8*)(
        V + ((size_t)(b * S_ + s0 + s)) * D_ + h * E_ + cs);
  }
  __syncthreads();
#pragma unroll
  for (int p = 0; p < 2; ++p) {
    int e = row + p * 32;
    ushort8 v;
#pragma unroll
    for (int i = 0; i < 8; ++i) v[i] = t[cs + i][e];
    *(ushort8*)(Vt + ((size_t)(bh * E_ + e)) * S_ + s0 + cs) = v;
  }
}

// ---------------------------------------------------------------------------
// Fused attention, softmax over HEADS, bf16 MFMA.  R10 structure:
// 1024 threads, 16 warps (1 head each), 32 q-rows per task, K-tile 32.
// Block (b,j): task A = even-kt half of qt=j; task B = odd-kt half of
// qt=31-j (+ uniform tail).  Partials atomicAdd'ed into zeroed fp32 P.
// LDS: scf[16][32][34] f32 (68KB, pad->2-way free) + at[16][32][40] (41KB).
// ---------------------------------------------------------------------------
__global__ __launch_bounds__(1024, 4) void attn_headsoftmax(
    const u16* __restrict__ Qg,   // [B][S][D] bf16
    const u16* __restrict__ Kg,   // [B][S][D] bf16
    const u16* __restrict__ Vt,   // [B*H][E][S] bf16
    float* __restrict__ P)        // [B][S][D] fp32, zeroed
{
  const int id   = blockIdx.x;         // 0..255; id&7 == b == XCD
  const int b    = id & 7;
  const int j    = id >> 3;            // 0..31
  const int tid  = threadIdx.x;
  const int h    = tid >> 6;
  const int lane = tid & 63;
  const int quad = lane >> 4;
  const int l16  = lane & 15;

  __shared__ float scf[16][32][34];    // fp32 scores (pad 34: writes 2-way)
  __shared__ u16   at[16][32][40];     // bf16 attn for PV A-frags

  const u16* Kh = Kg + (size_t)b * S_ * D_ + h * E_;
  const u16* Vh = Vt + ((size_t)(b * H_ + h) * E_) * S_;

  // 1/sqrt(8), correctly rounded fp32; s==0 <=> dot==0 under both forms.
  const float inv_rsq8 = 0.35355339059327373f;

  auto run_task = [&](int qt, int parity, int do_tail) {
    const int q0 = qt * 32;

    bf16x8 qf[2][2];
    {
      const u16* Qb = Qg + ((size_t)(b * S_ + q0)) * D_ + h * E_;
#pragma unroll
      for (int i = 0; i < 2; ++i)
#pragma unroll
        for (int c = 0; c < 2; ++c)
          qf[i][c] = *(const bf16x8*)(Qb + (size_t)(i * 16 + l16) * D_ +
                                      c * 32 + quad * 8);
    }

    f32x4 oacc[2][4];
#pragma unroll
    for (int i = 0; i < 2; ++i)
#pragma unroll
      for (int nc = 0; nc < 4; ++nc) oacc[i][nc] = (f32x4){0.f,0.f,0.f,0.f};

    bf16x8 vA[4], vB[4];
    auto loadV = [&](int kt, bf16x8 (&vf)[4]) {
      const u16* Vb = Vh + kt * 32;
#pragma unroll
      for (int nc = 0; nc < 4; ++nc)   // B: n=e (lane&15), k=s (quad*8+jj)
        vf[nc] = *(const bf16x8*)(Vb + (size_t)(nc * 16 + l16) * S_ +
                                  quad * 8);
    };

    // one iteration: QK(kt)->scf | prefetch V(kt+2) | bar | softmax | bar |
    // PV(kt) with vcur.  2 barriers; V loaded a full phase+2 bars early.
    auto step = [&](int kt, bf16x8 (&vcur)[4], bf16x8 (&vnxt)[4]) {
      const int k0 = kt * 32;
      {
        const u16* Kb = Kh + (size_t)k0 * D_;
        bf16x8 kf[2][2];
#pragma unroll
        for (int nc = 0; nc < 2; ++nc)
#pragma unroll
          for (int c = 0; c < 2; ++c)
            kf[nc][c] = *(const bf16x8*)(Kb + (size_t)(nc * 16 + l16) * D_ +
                                         c * 32 + quad * 8);
        f32x4 sacc[2][2];
#pragma unroll
        for (int i = 0; i < 2; ++i)
#pragma unroll
          for (int nc = 0; nc < 2; ++nc)
            sacc[i][nc] = (f32x4){0.f, 0.f, 0.f, 0.f};
#pragma unroll
        for (int c = 0; c < 2; ++c)
#pragma unroll
          for (int i = 0; i < 2; ++i)
#pragma unroll
            for (int nc = 0; nc < 2; ++nc)
              sacc[i][nc] = __builtin_amdgcn_mfma_f32_16x16x32_bf16(
                  qf[i][c], kf[nc][c], sacc[i][nc], 0, 0, 0);
#pragma unroll
        for (int i = 0; i < 2; ++i)
#pragma unroll
          for (int nc = 0; nc < 2; ++nc)
#pragma unroll
            for (int reg = 0; reg < 4; ++reg) {
              int qrow = i * 16 + quad * 4 + reg;  // C: row=quad*4+reg
              int kcol = nc * 16 + l16;            // C: col=lane&15
              float s = sacc[i][nc][reg] * inv_rsq8;
              if ((k0 + kcol > q0 + qrow) || (s == 0.0f)) s = -1e9f;
              scf[h][qrow][kcol] = s;
            }
      }
      if (kt + 2 <= qt) loadV(kt + 2, vnxt);   // prefetch next V early
      __syncthreads();
      {  // ---- softmax across 16 heads at this thread's (q,k) ----
        const int qq = tid >> 5, kk = tid & 31;
        float v[16];
        float m = -3.0e38f;
#pragma unroll
        for (int hh = 0; hh < 16; ++hh) {
          v[hh] = scf[hh][qq][kk];
          m = fmaxf(m, v[hh]);
        }
        float sum = 0.f;
#pragma unroll
        for (int hh = 0; hh < 16; ++hh) {
          v[hh] = __expf(v[hh] - m);   // exp(0)=1, exp(-1e9)=0 exact
          sum += v[hh];
        }
        float inv = 1.0f / sum;        // all-masked: 1/16 (pow2) -> exact
#pragma unroll
        for (int hh = 0; hh < 16; ++hh) at[hh][qq][kk] = f2b(v[hh] * inv);
      }
      __syncthreads();
      {  // ---- O += attn @ V (vcur arrived long ago) ----
        bf16x8 af[2];
#pragma unroll
        for (int i = 0; i < 2; ++i)    // A: m=q (lane&15), k=s (quad*8+jj)
          af[i] = *(const bf16x8*)(&at[h][i * 16 + l16][quad * 8]);
#pragma unroll
        for (int i = 0; i < 2; ++i)
#pragma unroll
          for (int nc = 0; nc < 4; ++nc)
            oacc[i][nc] = __builtin_amdgcn_mfma_f32_16x16x32_bf16(
                af[i], vcur[nc], oacc[i][nc], 0, 0, 0);
      }
    };

    int kt = parity;
    if (kt <= qt) {
      loadV(kt, vA);
      while (true) {
        step(kt, vA, vB); kt += 2; if (kt > qt) break;
        step(kt, vB, vA); kt += 2; if (kt > qt) break;
      }
    }

    // ---- uniform tail (odd task only): k>=q0+32 -> all heads masked ->
    // attn = 1/16 exactly; add (1/16) * sum_{s>=s0u} V[h][e][s].
    float suf[4] = {0.f, 0.f, 0.f, 0.f};
    if (do_tail) {
      const int s0u = q0 + 32;
      if (s0u < S_) {
        const int chunk = (S_ - s0u) >> 2;   // per-quad share, multiple of 8
#pragma unroll
        for (int nc = 0; nc < 4; ++nc) {
          const u16* vp = Vh + (size_t)(nc * 16 + l16) * S_ + s0u +
                          quad * chunk;
          float a = 0.f;
          for (int s = 0; s < chunk; s += 8) {
            ushort8 v8 = *(const ushort8*)(vp + s);
#pragma unroll
            for (int jj = 0; jj < 8; ++jj) a += b2f(v8[jj]);
          }
          suf[nc] = a;
        }
#pragma unroll
        for (int nc = 0; nc < 4; ++nc) {
          float a = suf[nc];
          a += __shfl_xor(a, 16);      // reduce across quad bits
          a += __shfl_xor(a, 32);
          suf[nc] = a * 0.0625f;       // * 1/16 (exact)
        }
      }
    }

    // ---- epilogue: accumulate partial into P (2 contributors/elem) ----
    float* Pb = P + ((size_t)(b * S_ + q0)) * D_ + h * E_;
#pragma unroll
    for (int i = 0; i < 2; ++i)
#pragma unroll
      for (int nc = 0; nc < 4; ++nc)
#pragma unroll
        for (int reg = 0; reg < 4; ++reg) {
          int qrow = i * 16 + quad * 4 + reg;
          int e    = nc * 16 + l16;
          unsafeAtomicAdd(&Pb[(size_t)qrow * D_ + e],
                          oacc[i][nc][reg] + suf[nc]);
        }
  };

  run_task(j, 0, 0);        // even-kt half of qt=j
  __syncthreads();          // LDS reuse boundary
  run_task(31 - j, 1, 1);   // odd-kt half of qt=31-j, + its tail
}

// ---------------------------------------------------------------------------
extern "C" void kernel_launch(void* const* d_in, const int* in_sizes, int n_in,
                              void* d_out, int out_size, void* d_ws,
                              size_t ws_size, hipStream_t stream)
{
  const float* X1 = (const float*)d_in[0];
  const float* X2 = (const float*)d_in[1];
  const float* Wq = (const float*)d_in[2];
  const float* bq = (const float*)d_in[3];
  const float* Wk = (const float*)d_in[4];
  const float* bk = (const float*)d_in[5];
  const float* Wv = (const float*)d_in[6];
  const float* bv = (const float*)d_in[7];
  const float* Wo = (const float*)d_in[8];
  const float* bo = (const float*)d_in[9];

  // Workspace (u16 units): X1b,X2b 8M each; Wt 1M x4; Qb,Kb,Vb,Vtb 8M each.
  // P (fp32 partial O, 32MB) aliases X1b+X2b (dead after QKV GEMMs).
  // AOb (bf16, 16MB) aliases Vb (dead after transpose_v). Total 88MB.
  u16* X1b = (u16*)d_ws;
  u16* X2b = X1b + (8u << 20);
  u16* WtQ = X2b + (8u << 20);
  u16* WtK = WtQ + (1u << 20);
  u16* WtV = WtK + (1u << 20);
  u16* WtO = WtV + (1u << 20);
  u16* Qb  = WtO + (1u << 20);
  u16* Kb  = Qb + (8u << 20);
  u16* Vb  = Kb + (8u << 20);
  u16* Vtb = Vb + (8u << 20);
  float* P = (float*)d_ws;   // 8192*1024 fp32 = 32MB = X1b+X2b region
  u16* AOb = Vb;             // alias

  cvt_bf16<<<4096, 256, 0, stream>>>(X1, X1b);
  cvt_bf16<<<4096, 256, 0, stream>>>(X2, X2b);

  dim3 tg(16, 16);
  trans_cvt_w<<<tg, 256, 0, stream>>>(Wq, WtQ);
  trans_cvt_w<<<tg, 256, 0, stream>>>(Wk, WtK);
  trans_cvt_w<<<tg, 256, 0, stream>>>(Wv, WtV);
  trans_cvt_w<<<tg, 256, 0, stream>>>(Wo, WtO);

  dim3 gg(64, 8);  // (M/128, N/128)
  gemm_bf16<<<gg, 256, 0, stream>>>(X1b, WtQ, bq, Qb, 8192, 1024, 1024, 0);
  gemm_bf16<<<gg, 256, 0, stream>>>(X2b, WtK, bk, Kb, 8192, 1024, 1024, 0);
  gemm_bf16<<<gg, 256, 0, stream>>>(X2b, WtV, bv, Vb, 8192, 1024, 1024, 0);

  transpose_v<<<dim3(16, 128), 256, 0, stream>>>(Vb, Vtb);

  // X1b/X2b dead now; zero P over their region, then accumulate partials.
  hipMemsetAsync(P, 0, (size_t)8192 * 1024 * 4, stream);

  attn_headsoftmax<<<dim3(256), 1024, 0, stream>>>(Qb, Kb, Vtb, P);

  cvt_bf16<<<4096, 256, 0, stream>>>(P, AOb);   // fp32 partial-sum -> bf16

  // Output fp32 (reference returns float32).
  gemm_bf16<<<gg, 256, 0, stream>>>(AOb, WtO, bo, d_out, 8192, 1024, 1024, 1);
}

// Round 4
// 474.324 us; speedup vs baseline: 1.1030x; 1.1030x over previous
//
#include <hip/hip_runtime.h>
#include <cstdint>

// ---------------------------------------------------------------------------
// MultiHeadAttention (B=8,S=1024,D=1024,H=16,E=64). Inputs fp32, output fp32.
// Quirks: scale = 1/sqrt(8) (d_k = batch quirk); tril + exact-zero -> -1e9
// (fp32, pre-round); softmax over HEADS axis (local per (b,q,k)).
//
// R11: triangle win with R7's PROVEN inner loop, untouched.
//  Evidence: R7 = 5.67us per 32-row iter (clean, VGPR=60). R8/R9/R10
//  restructures were 2.6x worse per work unit (16-row tiles / lambda+array
//  double-buffers -> scratch spills, WRITE_SIZE 333MB in R10).
//  This round changes ONLY loop bounds + work assignment:
//  - block (b,j), b=id&7 (XCD=batch -> K/V L2-resident, R9's FETCH win):
//      task0: kt in [0, ceil((j+1)/2))        of qt=j
//      task1: kt in [ceil((qt+1)/2), qt]      of qt=31-j, + uniform tail
//    -> 16-17 iters/block, deterministic balance, 256 blocks, 1/CU.
//  - straight-line R7 phase code (no lambdas, no reg double-buffer).
//  - partial O: fp32 unsafeAtomicAdd into zeroed P (exactly 2 commutative
//    contributors -> deterministic). P aliases X1b/X2b (dead).
//  - uniform tail: k>=(qt+1)*32 -> all 16 heads masked -> attn==1/16 exact
//    -> out += (1/16)*suffix-sum(V) (proven in R8-R10).
//  - scf pad 33->34 (bank conflicts halved in R9/R10, free).
// ---------------------------------------------------------------------------

typedef unsigned short u16;
typedef unsigned int   u32;
typedef __attribute__((ext_vector_type(8))) __bf16         bf16x8;
typedef __attribute__((ext_vector_type(8))) unsigned short ushort8;
typedef __attribute__((ext_vector_type(4))) float          f32x4;

#define S_ 1024
#define D_ 1024
#define H_ 16
#define E_ 64

__device__ __forceinline__ float b2f(u16 h) {
  union { u32 u; float f; } v; v.u = ((u32)h) << 16; return v.f;
}
__device__ __forceinline__ u16 f2b(float f) {      // round-to-nearest-even
  union { float f; u32 u; } v; v.f = f;
  u32 r = v.u + 0x7fffu + ((v.u >> 16) & 1u);
  return (u16)(r >> 16);
}

typedef const __attribute__((address_space(1))) u32 gu32;
typedef       __attribute__((address_space(3))) u32 lu32;

// 16B global->LDS direct load; LDS dest must be wave-uniform base + lane*16.
__device__ __forceinline__ void gload_lds16(const u16* g, u16* l) {
  __builtin_amdgcn_global_load_lds((gu32*)(uintptr_t)g, (lu32*)(uintptr_t)l,
                                   16, 0, 0);
}

// ---------------------------------------------------------------------------
// fp32 -> bf16 elementwise convert (n = multiple of 2048).
// ---------------------------------------------------------------------------
__global__ __launch_bounds__(256, 1) void cvt_bf16(
    const float* __restrict__ src, u16* __restrict__ dst)
{
  const size_t i = (size_t)blockIdx.x * 256 + threadIdx.x;
  float4 a = ((const float4*)src)[2 * i];
  float4 b = ((const float4*)src)[2 * i + 1];
  ushort8 o;
  o[0] = f2b(a.x); o[1] = f2b(a.y); o[2] = f2b(a.z); o[3] = f2b(a.w);
  o[4] = f2b(b.x); o[5] = f2b(b.y); o[6] = f2b(b.z); o[7] = f2b(b.w);
  ((ushort8*)dst)[i] = o;
}

// ---------------------------------------------------------------------------
// Weight transpose+convert: W fp32 [K][N] -> Wt bf16 [N][K]. 64x64 tiles.
// ---------------------------------------------------------------------------
__global__ __launch_bounds__(256, 1) void trans_cvt_w(
    const float* __restrict__ W, u16* __restrict__ Wt)
{
  __shared__ u16 t[64][72];
  const int k0 = blockIdx.x * 64, n0 = blockIdx.y * 64;
  const int row = threadIdx.x >> 3;
  const int cs  = (threadIdx.x & 7) * 8;
#pragma unroll
  for (int p = 0; p < 2; ++p) {
    int r = row + p * 32;
    const float* Wp = W + (size_t)(k0 + r) * 1024 + n0 + cs;
    float4 a = *(const float4*)(Wp);
    float4 b = *(const float4*)(Wp + 4);
    u16* tp = &t[r][cs];
    tp[0] = f2b(a.x); tp[1] = f2b(a.y); tp[2] = f2b(a.z); tp[3] = f2b(a.w);
    tp[4] = f2b(b.x); tp[5] = f2b(b.y); tp[6] = f2b(b.z); tp[7] = f2b(b.w);
  }
  __syncthreads();
#pragma unroll
  for (int p = 0; p < 2; ++p) {
    int n = row + p * 32;
    ushort8 v;
#pragma unroll
    for (int i = 0; i < 8; ++i) v[i] = t[cs + i][n];
    *(ushort8*)(Wt + (size_t)(n0 + n) * 1024 + k0 + cs) = v;
  }
}

// ---------------------------------------------------------------------------
// bf16 MFMA GEMM: C[M][N] = A[M][K] @ Bt[N][K]^T + bias[N] (fp32 accum).
// 128x128 tile, BK=32, 256 threads / 4 waves. m97-style global_load_lds
// width-16 staging. out_f32: 1 -> fp32 stores, 0 -> bf16 stores.
// ---------------------------------------------------------------------------
__global__ __launch_bounds__(256, 1) void gemm_bf16(
    const u16* __restrict__ A, const u16* __restrict__ Bt,
    const float* __restrict__ bias, void* __restrict__ Cv,
    int M, int N, int K, int out_f32)
{
  __shared__ u16 As[128 * 32];   // [m][k] row-major, 8KB
  __shared__ u16 Bs[128 * 32];   // [n][k] row-major, 8KB
  const int tid  = threadIdx.x;
  const int wave = tid >> 6;
  const int lane = tid & 63;
  const int quad = lane >> 4;
  const int l16  = lane & 15;
  const int m0   = (wave & 1) * 64;
  const int n0   = (wave >> 1) * 64;

  const u16* Ab = A  + (size_t)blockIdx.x * 128 * K;
  const u16* Bb = Bt + (size_t)blockIdx.y * 128 * K;

  f32x4 acc[4][4];
#pragma unroll
  for (int i = 0; i < 4; ++i)
#pragma unroll
    for (int j = 0; j < 4; ++j) acc[i][j] = (f32x4){0.f, 0.f, 0.f, 0.f};

  for (int kb = 0; kb < K; kb += 32) {
    __syncthreads();               // prior iter's LDS reads done
#pragma unroll
    for (int p = 0; p < 2; ++p) {  // 512 16B segs over 256 threads
      int seg = tid + p * 256;     // = (wave*64+p*256) + lane -> base+lane*16
      int row = seg >> 2, ks = seg & 3;
      gload_lds16(Ab + (size_t)row * K + kb + ks * 8, As + seg * 8);
      gload_lds16(Bb + (size_t)row * K + kb + ks * 8, Bs + seg * 8);
    }
    __builtin_amdgcn_s_waitcnt(0); // drain vmcnt before barrier
    __syncthreads();

    bf16x8 af[4], bfr[4];
#pragma unroll
    for (int i = 0; i < 4; ++i)    // A-frag: m=lane&15, k=quad*8+j
      af[i] = *(const bf16x8*)(As + (m0 + i * 16 + l16) * 32 + quad * 8);
#pragma unroll
    for (int j = 0; j < 4; ++j)    // B-frag: n=lane&15, k=quad*8+j
      bfr[j] = *(const bf16x8*)(Bs + (n0 + j * 16 + l16) * 32 + quad * 8);
#pragma unroll
    for (int i = 0; i < 4; ++i)
#pragma unroll
      for (int j = 0; j < 4; ++j)
        acc[i][j] = __builtin_amdgcn_mfma_f32_16x16x32_bf16(
            af[i], bfr[j], acc[i][j], 0, 0, 0);
  }

  float bv[4];
#pragma unroll
  for (int j = 0; j < 4; ++j)
    bv[j] = bias[(size_t)blockIdx.y * 128 + n0 + j * 16 + l16];

  if (out_f32) {
    float* C = (float*)Cv;
#pragma unroll
    for (int i = 0; i < 4; ++i) {
      int r = blockIdx.x * 128 + m0 + i * 16 + quad * 4;   // row=quad*4+reg
#pragma unroll
      for (int j = 0; j < 4; ++j) {
        int c = blockIdx.y * 128 + n0 + j * 16 + l16;      // col=lane&15
#pragma unroll
        for (int reg = 0; reg < 4; ++reg)
          C[(size_t)(r + reg) * N + c] = acc[i][j][reg] + bv[j];
      }
    }
  } else {
    u16* C = (u16*)Cv;
#pragma unroll
    for (int i = 0; i < 4; ++i) {
      int r = blockIdx.x * 128 + m0 + i * 16 + quad * 4;
#pragma unroll
      for (int j = 0; j < 4; ++j) {
        int c = blockIdx.y * 128 + n0 + j * 16 + l16;
#pragma unroll
        for (int reg = 0; reg < 4; ++reg)
          C[(size_t)(r + reg) * N + c] = f2b(acc[i][j][reg] + bv[j]);
      }
    }
  }
}

// ---------------------------------------------------------------------------
// V transpose (bf16): V[b][s][h*64+e] -> Vt[(b*16+h)*64+e][s]  (per-head E,S)
// ---------------------------------------------------------------------------
__global__ __launch_bounds__(256, 1) void transpose_v(
    const u16* __restrict__ V, u16* __restrict__ Vt)
{
  __shared__ u16 t[64][72];
  const int s0 = blockIdx.x * 64;
  const int bh = blockIdx.y;           // b*16 + h
  const int b = bh >> 4, h = bh & 15;
  const int row = threadIdx.x >> 3;
  const int cs  = (threadIdx.x & 7) * 8;
#pragma unroll
  for (int p = 0; p < 2; ++p) {
    int s = row + p * 32;
    *(ushort8*)(&t[s][cs]) = *(const ushort8*)(
        V + ((size_t)(b * S_ + s0 + s)) * D_ + h * E_ + cs);
  }
  __syncthreads();
#pragma unroll
  for (int p = 0; p < 2; ++p) {
    int e = row + p * 32;
    ushort8 v;
#pragma unroll
    for (int i = 0; i < 8; ++i) v[i] = t[cs + i][e];
    *(ushort8*)(Vt + ((size_t)(bh * E_ + e)) * S_ + s0 + cs) = v;
  }
}

// ---------------------------------------------------------------------------
// Fused attention, softmax over HEADS, bf16 MFMA.  R11:
// R7's exact 32-q-row/1024-thread/16-warp/3-barrier inner loop; block (b,j)
// runs task0 = front half of qt=j's k-range, task1 = back half of qt=31-j's
// k-range + uniform tail.  Partials -> fp32 unsafeAtomicAdd into zeroed P.
// LDS: scf[16][32][34] f32 (69.6KB) + at[16][32][40] u16 (41KB) = 110.6KB.
// ---------------------------------------------------------------------------
__global__ __launch_bounds__(1024, 4) void attn_headsoftmax(
    const u16* __restrict__ Qg,   // [B][S][D] bf16
    const u16* __restrict__ Kg,   // [B][S][D] bf16
    const u16* __restrict__ Vt,   // [B*H][E][S] bf16
    float* __restrict__ P)        // [B][S][D] fp32, zeroed
{
  const int id   = blockIdx.x;         // 0..255; id&7 == b == XCD
  const int b    = id & 7;
  const int j    = id >> 3;            // 0..31
  const int tid  = threadIdx.x;
  const int h    = tid >> 6;
  const int lane = tid & 63;
  const int quad = lane >> 4;
  const int l16  = lane & 15;

  __shared__ float scf[16][32][34];    // fp32 scores (pad 34)
  __shared__ u16   at[16][32][40];     // bf16 attn for PV A-frags

  const u16* Kh = Kg + (size_t)b * S_ * D_ + h * E_;
  const u16* Vh = Vt + ((size_t)(b * H_ + h) * E_) * S_;

  // 1/sqrt(8), correctly rounded fp32; s==0 <=> dot==0 under both forms.
  const float inv_rsq8 = 0.35355339059327373f;

#pragma unroll 1
  for (int task = 0; task < 2; ++task) {
    const int qt   = task ? (31 - j) : j;
    const int q0   = qt * 32;
    const int half = (qt + 2) >> 1;            // ceil((qt+1)/2)
    const int ktLo = task ? half : 0;
    const int ktHi = task ? qt : (half - 1);   // inclusive

    // ---- Q fragments (R7 verbatim) ----
    bf16x8 qf[2][2];
    {
      const u16* Qb = Qg + ((size_t)(b * S_ + q0)) * D_ + h * E_;
#pragma unroll
      for (int i = 0; i < 2; ++i)
#pragma unroll
        for (int c = 0; c < 2; ++c)
          qf[i][c] = *(const bf16x8*)(Qb + (size_t)(i * 16 + l16) * D_ +
                                      c * 32 + quad * 8);
    }

    f32x4 oacc[2][4];
#pragma unroll
    for (int i = 0; i < 2; ++i)
#pragma unroll
      for (int nc = 0; nc < 4; ++nc) oacc[i][nc] = (f32x4){0.f,0.f,0.f,0.f};

    for (int kt = ktLo; kt <= ktHi; ++kt) {
      const int k0 = kt * 32;
      {  // ---- scores = Q K^T * (1/sqrt8), mask, -> LDS fp32 ----
        const u16* Kb = Kh + (size_t)k0 * D_;
        bf16x8 kf[2][2];
#pragma unroll
        for (int nc = 0; nc < 2; ++nc)
#pragma unroll
          for (int c = 0; c < 2; ++c)
            kf[nc][c] = *(const bf16x8*)(Kb + (size_t)(nc * 16 + l16) * D_ +
                                         c * 32 + quad * 8);
        f32x4 sacc[2][2];
#pragma unroll
        for (int i = 0; i < 2; ++i)
#pragma unroll
          for (int nc = 0; nc < 2; ++nc)
            sacc[i][nc] = (f32x4){0.f, 0.f, 0.f, 0.f};
#pragma unroll
        for (int c = 0; c < 2; ++c)
#pragma unroll
          for (int i = 0; i < 2; ++i)
#pragma unroll
            for (int nc = 0; nc < 2; ++nc)
              sacc[i][nc] = __builtin_amdgcn_mfma_f32_16x16x32_bf16(
                  qf[i][c], kf[nc][c], sacc[i][nc], 0, 0, 0);
#pragma unroll
        for (int i = 0; i < 2; ++i)
#pragma unroll
          for (int nc = 0; nc < 2; ++nc)
#pragma unroll
            for (int reg = 0; reg < 4; ++reg) {
              int qrow = i * 16 + quad * 4 + reg;  // C: row=quad*4+reg
              int kcol = nc * 16 + l16;            // C: col=lane&15
              float s = sacc[i][nc][reg] * inv_rsq8;
              if ((k0 + kcol > q0 + qrow) || (s == 0.0f)) s = -1e9f;
              scf[h][qrow][kcol] = s;
            }
      }
      __syncthreads();
      {  // ---- softmax across 16 heads at this thread's (q,k) ----
        const int qq = tid >> 5, kk = tid & 31;
        float v[16];
        float m = -3.0e38f;
#pragma unroll
        for (int hh = 0; hh < 16; ++hh) {
          v[hh] = scf[hh][qq][kk];
          m = fmaxf(m, v[hh]);
        }
        float sum = 0.f;
#pragma unroll
        for (int hh = 0; hh < 16; ++hh) {
          v[hh] = __expf(v[hh] - m);   // exp(0)=1, exp(-1e9)=0 exact
          sum += v[hh];
        }
        float inv = 1.0f / sum;        // all-masked: 1/16 (pow2) -> exact
#pragma unroll
        for (int hh = 0; hh < 16; ++hh) at[hh][qq][kk] = f2b(v[hh] * inv);
      }
      __syncthreads();
      {  // ---- O += attn @ V (R7 verbatim: V loaded inline) ----
        bf16x8 af[2];
#pragma unroll
        for (int i = 0; i < 2; ++i)    // A: m=q (lane&15), k=s (quad*8+jj)
          af[i] = *(const bf16x8*)(&at[h][i * 16 + l16][quad * 8]);
        const u16* Vb = Vh + k0;
        bf16x8 vf[4];
#pragma unroll
        for (int nc = 0; nc < 4; ++nc) // B: n=e (lane&15), k=s (quad*8+jj)
          vf[nc] = *(const bf16x8*)(Vb + (size_t)(nc * 16 + l16) * S_ +
                                    quad * 8);
#pragma unroll
        for (int i = 0; i < 2; ++i)
#pragma unroll
          for (int nc = 0; nc < 4; ++nc)
            oacc[i][nc] = __builtin_amdgcn_mfma_f32_16x16x32_bf16(
                af[i], vf[nc], oacc[i][nc], 0, 0, 0);
      }
      __syncthreads();
    }

    // ---- uniform tail (task1 only): k >= (qt+1)*32 -> all heads masked ->
    // attn = 1/16 exactly; add (1/16) * sum_{s>=s0u} V[h][e][s].
    float suf[4] = {0.f, 0.f, 0.f, 0.f};
    if (task == 1) {
      const int s0u = (qt + 1) * 32;
      if (s0u < S_) {
        const int chunk = (S_ - s0u) >> 2;   // per-quad share, multiple of 8
#pragma unroll
        for (int nc = 0; nc < 4; ++nc) {
          const u16* vp = Vh + (size_t)(nc * 16 + l16) * S_ + s0u +
                          quad * chunk;
          float a = 0.f;
          for (int s = 0; s < chunk; s += 8) {
            ushort8 v8 = *(const ushort8*)(vp + s);
#pragma unroll
            for (int jj = 0; jj < 8; ++jj) a += b2f(v8[jj]);
          }
          suf[nc] = a;
        }
#pragma unroll
        for (int nc = 0; nc < 4; ++nc) {
          float a = suf[nc];
          a += __shfl_xor(a, 16);      // reduce across quad bits
          a += __shfl_xor(a, 32);
          suf[nc] = a * 0.0625f;       // * 1/16 (exact)
        }
      }
    }

    // ---- epilogue: accumulate partial into P (2 contributors/elem) ----
    float* Pb = P + ((size_t)(b * S_ + q0)) * D_ + h * E_;
#pragma unroll
    for (int i = 0; i < 2; ++i)
#pragma unroll
      for (int nc = 0; nc < 4; ++nc)
#pragma unroll
        for (int reg = 0; reg < 4; ++reg) {
          int qrow = i * 16 + quad * 4 + reg;
          int e    = nc * 16 + l16;
          unsafeAtomicAdd(&Pb[(size_t)qrow * D_ + e],
                          oacc[i][nc][reg] + suf[nc]);
        }
    __syncthreads();   // LDS reuse boundary before next task
  }
}

// ---------------------------------------------------------------------------
extern "C" void kernel_launch(void* const* d_in, const int* in_sizes, int n_in,
                              void* d_out, int out_size, void* d_ws,
                              size_t ws_size, hipStream_t stream)
{
  const float* X1 = (const float*)d_in[0];
  const float* X2 = (const float*)d_in[1];
  const float* Wq = (const float*)d_in[2];
  const float* bq = (const float*)d_in[3];
  const float* Wk = (const float*)d_in[4];
  const float* bk = (const float*)d_in[5];
  const float* Wv = (const float*)d_in[6];
  const float* bv = (const float*)d_in[7];
  const float* Wo = (const float*)d_in[8];
  const float* bo = (const float*)d_in[9];

  // Workspace (u16 units): X1b,X2b 8M each; Wt 1M x4; Qb,Kb,Vb,Vtb 8M each.
  // P (fp32 partial O, 32MB) aliases X1b+X2b (dead after QKV GEMMs).
  // AOb (bf16, 16MB) aliases Vb (dead after transpose_v). Total 88MB.
  u16* X1b = (u16*)d_ws;
  u16* X2b = X1b + (8u << 20);
  u16* WtQ = X2b + (8u << 20);
  u16* WtK = WtQ + (1u << 20);
  u16* WtV = WtK + (1u << 20);
  u16* WtO = WtV + (1u << 20);
  u16* Qb  = WtO + (1u << 20);
  u16* Kb  = Qb + (8u << 20);
  u16* Vb  = Kb + (8u << 20);
  u16* Vtb = Vb + (8u << 20);
  float* P = (float*)d_ws;   // 8192*1024 fp32 = 32MB = X1b+X2b region
  u16* AOb = Vb;             // alias

  cvt_bf16<<<4096, 256, 0, stream>>>(X1, X1b);
  cvt_bf16<<<4096, 256, 0, stream>>>(X2, X2b);

  dim3 tg(16, 16);
  trans_cvt_w<<<tg, 256, 0, stream>>>(Wq, WtQ);
  trans_cvt_w<<<tg, 256, 0, stream>>>(Wk, WtK);
  trans_cvt_w<<<tg, 256, 0, stream>>>(Wv, WtV);
  trans_cvt_w<<<tg, 256, 0, stream>>>(Wo, WtO);

  dim3 gg(64, 8);  // (M/128, N/128)
  gemm_bf16<<<gg, 256, 0, stream>>>(X1b, WtQ, bq, Qb, 8192, 1024, 1024, 0);
  gemm_bf16<<<gg, 256, 0, stream>>>(X2b, WtK, bk, Kb, 8192, 1024, 1024, 0);
  gemm_bf16<<<gg, 256, 0, stream>>>(X2b, WtV, bv, Vb, 8192, 1024, 1024, 0);

  transpose_v<<<dim3(16, 128), 256, 0, stream>>>(Vb, Vtb);

  // X1b/X2b dead now; zero P over their region, then accumulate partials.
  hipMemsetAsync(P, 0, (size_t)8192 * 1024 * 4, stream);

  attn_headsoftmax<<<dim3(256), 1024, 0, stream>>>(Qb, Kb, Vtb, P);

  cvt_bf16<<<4096, 256, 0, stream>>>(P, AOb);   // fp32 partial-sum -> bf16

  // Output fp32 (reference returns float32).
  gemm_bf16<<<gg, 256, 0, stream>>>(AOb, WtO, bo, d_out, 8192, 1024, 1024, 1);
}